// Round 2
// baseline (905.626 us; speedup 1.0000x reference)
//
#include <hip/hip_runtime.h>

#define NN 4096
#define NSTEPS 100
#define TPB 512
#define NBLK 256     // 1 block per CU; 16 rows per block, K pinned in VGPRs
#define CSTRIDE 32   // u32 stride between per-step counters: 128B = own IC line

// Coherent (cross-XCD) load/store: relaxed agent-scope atomics compile to
// sc-flagged global ops that bypass the non-coherent L1/L2 and hit the
// coherence point directly — WITHOUT the buffer_wbl2 / buffer_inv cache
// maintenance that release/acquire fences emit.
__device__ __forceinline__ void zstore_u64(float2* p, unsigned long long u) {
    __hip_atomic_store((unsigned long long*)p, u, __ATOMIC_RELAXED,
                       __HIP_MEMORY_SCOPE_AGENT);
}
__device__ __forceinline__ unsigned long long zload_u64(const float2* p) {
    return __hip_atomic_load((const unsigned long long*)p, __ATOMIC_RELAXED,
                             __HIP_MEMORY_SCOPE_AGENT);
}
__device__ __forceinline__ unsigned cload_u32(const unsigned* p) {
    return __hip_atomic_load(p, __ATOMIC_RELAXED, __HIP_MEMORY_SCOPE_AGENT);
}

// R3: counter-gated exchange. The R2 profile showed the step period dominated
// by data-polling: every retry round re-read the full (mostly stale) payload
// through the coherence point (~8 MB/round grid-wide). Now the flag is
// SEPARATE from the payload: producers publish 16 elements (sc stores), drain
// with s_waitcnt vmcnt(0) (sc stores retire at the coherence point, so no
// release-fence cache maintenance is needed), then ONE relaxed agent-scope
// atomicAdd on cnt[s+1]. Consumers gate on cnt[s]==NBLK — polled by wave 0
// only, broadcast to sibling waves via an LDS flag — then do a SINGLE pass of
// sc data loads. Counters are 128B-padded so step-s polls don't contend with
// step-(s+1) increments. Tags are gone; zb needs no memset (gated), only cnt.
//
// Cross-step LDS overwrite guard: passing gate s+1 requires cnt[s+1]==NBLK,
// which requires THIS block's wave-0 atomic, which is issued after wave 0's
// ODE reads of zr/zi — so no wave can restage LDS while any wave still reads.
__global__ __launch_bounds__(TPB, 2) void k_persist(
    const float* __restrict__ K, const float2* __restrict__ z0,
    float2* __restrict__ zb0, float2* __restrict__ zb1,
    unsigned* __restrict__ cnt,
    float2* __restrict__ zfinal, const float* __restrict__ omega_p,
    const float* __restrict__ dt_p) {
    __shared__ float zr[NN];
    __shared__ float zi[NN];
    __shared__ float P[8][8];
    __shared__ int gateLds;   // last step whose gate wave 0 confirmed

    const int tid  = threadIdx.x;
    const int bid  = blockIdx.x;
    const int w    = tid >> 6, lane = tid & 63;
    const int g    = w >> 1,   h    = w & 1;
    const int rb   = bid * 16 + g * 4;          // first of this wave's 4 rows
    const int cb   = h * 2048 + lane * 4;       // lane's col base (j stride 256)

    const float omega = *omega_p;
    const float dt    = *dt_p;
    const float inv2n = 1.0f / (2.0f * NN);

    if (tid == 0) gateLds = 0;   // published by the s==0 __syncthreads

    // ---- load K fragment: 4 rows x 8 float4 = 128 VGPRs ----
    float4 kA[4][8];
#pragma unroll
    for (int r = 0; r < 4; ++r) {
        const float* Kr = K + (size_t)(rb + r) * NN + cb;
#pragma unroll
        for (int j = 0; j < 8; ++j) kA[r][j] = *(const float4*)(Kr + j * 256);
    }

    for (int s = 0; s < NSTEPS; ++s) {
        // Pin kA in registers: opaque redefinition each iteration so the
        // compiler can neither spill-and-reload nor refold the global loads.
#pragma unroll
        for (int r = 0; r < 4; ++r)
#pragma unroll
            for (int j = 0; j < 8; ++j)
                asm volatile("" : "+v"(kA[r][j].x), "+v"(kA[r][j].y),
                                  "+v"(kA[r][j].z), "+v"(kA[r][j].w));

        // ---- gate + stage z_s -> LDS (SoA), conflict-free ----
        if (s == 0) {
#pragma unroll
            for (int it = 0; it < 8; ++it) {
                int idx = it * TPB + tid;
                float2 v = z0[idx];
                zr[idx] = v.x; zi[idx] = v.y;
            }
        } else {
            if (w == 0) {
                const unsigned* cs = cnt + (size_t)s * CSTRIDE;
                while (cload_u32(cs) < NBLK) __builtin_amdgcn_s_sleep(1);
                __hip_atomic_store(&gateLds, s, __ATOMIC_RELAXED,
                                   __HIP_MEMORY_SCOPE_WORKGROUP);
            } else {
                while (__hip_atomic_load(&gateLds, __ATOMIC_RELAXED,
                                         __HIP_MEMORY_SCOPE_WORKGROUP) < s)
                    __builtin_amdgcn_s_sleep(1);
            }
            const float2* zsrc = (s & 1) ? zb1 : zb0;
            unsigned long long v[8];
#pragma unroll
            for (int it = 0; it < 8; ++it)       // 8 sc loads in flight, once
                v[it] = zload_u64(zsrc + it * TPB + tid);
#pragma unroll
            for (int it = 0; it < 8; ++it) {
                union { unsigned u; float f; } cx, cy;
                cx.u = (unsigned)v[it];
                cy.u = (unsigned)(v[it] >> 32);
                int idx = it * TPB + tid;
                zr[idx] = cx.f; zi[idx] = cy.f;
            }
        }
        __syncthreads();

        // ---- dots: 4 rows x 2048 cols per wave, K from regs, z from LDS ----
        float sr0 = 0, sr1 = 0, sr2 = 0, sr3 = 0;
        float si0 = 0, si1 = 0, si2 = 0, si3 = 0;
#pragma unroll
        for (int j = 0; j < 8; ++j) {
            float4 a = *(const float4*)&zr[cb + j * 256];
            float4 b = *(const float4*)&zi[cb + j * 256];
            float4 k0 = kA[0][j], k1 = kA[1][j], k2 = kA[2][j], k3 = kA[3][j];
            sr0 += k0.x * a.x + k0.y * a.y + k0.z * a.z + k0.w * a.w;
            si0 += k0.x * b.x + k0.y * b.y + k0.z * b.z + k0.w * b.w;
            sr1 += k1.x * a.x + k1.y * a.y + k1.z * a.z + k1.w * a.w;
            si1 += k1.x * b.x + k1.y * b.y + k1.z * b.z + k1.w * b.w;
            sr2 += k2.x * a.x + k2.y * a.y + k2.z * a.z + k2.w * a.w;
            si2 += k2.x * b.x + k2.y * b.y + k2.z * b.z + k2.w * b.w;
            sr3 += k3.x * a.x + k3.y * a.y + k3.z * a.z + k3.w * a.w;
            si3 += k3.x * b.x + k3.y * b.y + k3.z * b.z + k3.w * b.w;
        }
#pragma unroll
        for (int off = 32; off; off >>= 1) {
            sr0 += __shfl_xor(sr0, off, 64); si0 += __shfl_xor(si0, off, 64);
            sr1 += __shfl_xor(sr1, off, 64); si1 += __shfl_xor(si1, off, 64);
            sr2 += __shfl_xor(sr2, off, 64); si2 += __shfl_xor(si2, off, 64);
            sr3 += __shfl_xor(sr3, off, 64); si3 += __shfl_xor(si3, off, 64);
        }
        if (lane == 0) {
            P[w][0] = sr0; P[w][1] = sr1; P[w][2] = sr2; P[w][3] = sr3;
            P[w][4] = si0; P[w][5] = si1; P[w][6] = si2; P[w][7] = si3;
        }
        __syncthreads();

        // ---- per-row ODE update (wave 0, threads 0..15) + publish ----
        if (w == 0) {
            if (lane < 16) {
                int g2 = lane >> 2, i = lane & 3;
                float u = P[2 * g2][i]     + P[2 * g2 + 1][i];      // Re(K z)
                float v = P[2 * g2][4 + i] + P[2 * g2 + 1][4 + i];  // Im(K z)
                int gr = bid * 16 + lane;
                float x = zr[gr], y = zi[gr];
                float A = x * x - y * y;           // Re(z^2)
                float B = 2.0f * x * y;            // Im(z^2)
                float dzr = inv2n * (u - (u * A + v * B)) + omega * x;
                float dzi = inv2n * (v - (u * B - v * A)) + omega * y;
                float nx = x + dt * dzr;
                float ny = y + dt * dzi;
                float a2 = nx * nx + ny * ny;
                if (a2 >= 0.999f * 0.999f) {
                    float sc = 0.999f / sqrtf(a2);
                    nx *= sc; ny *= sc;
                }
                if (s == NSTEPS - 1) {
                    zfinal[gr] = make_float2(nx, ny);    // plain store
                } else {
                    union { float f; unsigned u; } cx, cy;
                    cx.f = nx; cy.f = ny;
                    unsigned long long pk =
                        (unsigned long long)cx.u |
                        ((unsigned long long)cy.u << 32);
                    float2* zo = ((s + 1) & 1) ? zb1 : zb0;
                    zstore_u64(zo + gr, pk);             // fire-and-forget
                }
            }
            if (s < NSTEPS - 1) {
                // sc stores retire at the coherence point: vmcnt(0) == visible
                asm volatile("s_waitcnt vmcnt(0)" ::: "memory");
                if (lane == 0)
                    __hip_atomic_fetch_add(
                        (unsigned*)(cnt + (size_t)(s + 1) * CSTRIDE), 1u,
                        __ATOMIC_RELAXED, __HIP_MEMORY_SCOPE_AGENT);
            }
        }
        // no trailing barrier — the counter gate is the cross-step sync
    }
}

// ---- generic fallback: per-step launches ----
__global__ __launch_bounds__(256) void k_step_f32(
    const float* __restrict__ K, const float2* __restrict__ zin,
    float2* __restrict__ zout, const float* __restrict__ omega_p,
    const float* __restrict__ dt_p, int n) {
    const int wave = threadIdx.x >> 6;
    const int lane = threadIdx.x & 63;
    const int row  = blockIdx.x * 4 + wave;
    if (row >= n) return;
    float sr = 0.0f, si = 0.0f;
    for (int c = lane; c < n; c += 64) {
        float k = K[(size_t)row * n + c];
        float2 z = zin[c];
        sr += k * z.x;
        si += k * z.y;
    }
#pragma unroll
    for (int off = 32; off; off >>= 1) {
        sr += __shfl_down(sr, off, 64);
        si += __shfl_down(si, off, 64);
    }
    if (lane == 0) {
        float u = sr, v = si;
        float2 zc = zin[row];
        float x = zc.x, y = zc.y;
        float inv2n = 1.0f / (2.0f * n);
        float A = x * x - y * y, B = 2.0f * x * y;
        float dzr = inv2n * (u - (u * A + v * B)) + (*omega_p) * x;
        float dzi = inv2n * (v - (u * B - v * A)) + (*omega_p) * y;
        float nx = x + (*dt_p) * dzr, ny = y + (*dt_p) * dzi;
        float a2 = nx * nx + ny * ny;
        if (a2 >= 0.999f * 0.999f) { float sc = 0.999f / sqrtf(a2); nx *= sc; ny *= sc; }
        zout[row] = make_float2(nx, ny);
    }
}

extern "C" void kernel_launch(void* const* d_in, const int* in_sizes, int n_in,
                              void* d_out, int out_size, void* d_ws, size_t ws_size,
                              hipStream_t stream) {
    const float2* z0      = (const float2*)d_in[0];
    const float*  K       = (const float*)d_in[1];
    const float*  omega_p = (const float*)d_in[2];
    const float*  dt_p    = (const float*)d_in[3];
    const int n = in_sizes[0] / 2;
    float2* out = (float2*)d_out;

    const size_t zbytes   = 2 * (size_t)NN * sizeof(float2);      // two z bufs
    const size_t cntbytes = (size_t)NSTEPS * CSTRIDE * sizeof(unsigned);
    const size_t need     = zbytes + cntbytes;
    if (n == NN && ws_size >= need) {
        float2*   zb0 = (float2*)d_ws;
        float2*   zb1 = zb0 + NN;
        unsigned* cnt = (unsigned*)((char*)d_ws + zbytes);
        // only the counters need zeroing — z buffers are gated by cnt
        hipMemsetAsync(cnt, 0, cntbytes, stream);
        k_persist<<<NBLK, TPB, 0, stream>>>(K, z0, zb0, zb1, cnt, out,
                                            omega_p, dt_p);
    } else {
        float2* zb0 = (float2*)d_ws;
        float2* zb1 = zb0 + n;
        const float2* cur = z0;
        for (int s = 0; s < NSTEPS; ++s) {
            float2* nxt = (s == NSTEPS - 1) ? out : ((s & 1) ? zb1 : zb0);
            k_step_f32<<<(n + 3) / 4, 256, 0, stream>>>(K, cur, nxt, omega_p, dt_p, n);
            cur = nxt;
        }
    }
}

// Round 3
// 457.827 us; speedup vs baseline: 1.9781x; 1.9781x over previous
//
#include <hip/hip_runtime.h>

#define NN 4096
#define NSTEPS 100
#define TPB 512
#define NBLK 256     // 1 block per CU; 16 rows per block, K pinned in VGPRs

// Coherent (cross-XCD) 8-byte load/store: relaxed agent-scope atomics compile
// to sc-flagged global ops that bypass the non-coherent L1/L2 and hit the
// coherence point directly — no release/acquire cache-maintenance.
__device__ __forceinline__ void zstore_u64(float2* p, unsigned long long u) {
    __hip_atomic_store((unsigned long long*)p, u, __ATOMIC_RELAXED,
                       __HIP_MEMORY_SCOPE_AGENT);
}
__device__ __forceinline__ unsigned long long zload_u64(const float2* p) {
    return __hip_atomic_load((const unsigned long long*)p, __ATOMIC_RELAXED,
                             __HIP_MEMORY_SCOPE_AGENT);
}

// R4: direct-to-register tagged exchange, no z LDS staging.
//  - 8 waves = 8 disjoint column-eighths (512 cols each) x 16 rows. Each
//    thread consumes exactly 8 z elements (cols w*512 + lane + j*64) loaded
//    straight into registers with tagged sc loads (R2's proven protocol:
//    tag = step&7 in x-mantissa LSBs, batched re-poll of stale elements).
//    => each wave gates on only 32 producer blocks, not 256; arrival latency
//    is NOT amplified by a block-wide stage barrier; z redundancy is 1.
//  - Cross-lane reduce: distribute-and-halve butterfly (31 shuffles/thread
//    for 32 accumulators, vs 192 naive): each round ships half the live
//    values to the xor-partner and keeps the half whose index bit matches the
//    lane bit. After 5 rounds lane l holds acc index (l&31) summed over its
//    32-lane half; both halves written to P[par][w][0..63].
//  - ODE state (x,y) lives in wave-0 registers across steps — block b's rows
//    ARE block b's previous outputs, so no reload through the IC.
//  - P is double-buffered by step parity; ONE barrier per step. Safety of the
//    (s+2)-write vs (s)-read on the same parity: any wave's step-(s+2) gate
//    requires its producers' tag-(s+2) publishes, which require THOSE blocks'
//    step-(s+1) barriers, which require ALL 256 blocks' tag-(s+1) publishes —
//    including ours, which is program-after our wave-0's step-s P-read.
__global__ __launch_bounds__(TPB, 2) void k_persist(
    const float* __restrict__ K, const float2* __restrict__ z0,
    float2* __restrict__ zb0, float2* __restrict__ zb1,
    float2* __restrict__ zfinal, const float* __restrict__ omega_p,
    const float* __restrict__ dt_p) {
    __shared__ float P[2][8][64];

    const int tid  = threadIdx.x;
    const int bid  = blockIdx.x;
    const int w    = tid >> 6, lane = tid & 63;   // w = column-eighth
    const int colbase = w * 512 + lane;           // col_j = colbase + j*64

    const float omega = *omega_p;
    const float dt    = *dt_p;
    const float inv2n = 1.0f / (2.0f * NN);

    // ---- K fragment: 16 rows x 8 strided cols = 128 scalars in VGPRs ----
    // (instruction (r,j): lanes read consecutive floats -> coalesced)
    float kA[16][8];
#pragma unroll
    for (int r = 0; r < 16; ++r) {
        const float* Kr = K + (size_t)(bid * 16 + r) * NN + colbase;
#pragma unroll
        for (int j = 0; j < 8; ++j) kA[r][j] = Kr[j * 64];
    }

    // ---- persistent ODE state: this block's own 16 oscillators ----
    float x = 0.f, y = 0.f;
    if (w == 0 && lane < 16) {
        float2 zc = z0[bid * 16 + lane];
        x = zc.x; y = zc.y;
    }

    for (int s = 0; s < NSTEPS; ++s) {
        // Pin kA in registers: opaque redefinition each iteration so the
        // compiler can neither spill-and-reload nor refold the global loads.
#pragma unroll
        for (int r = 0; r < 16; ++r)
#pragma unroll
            for (int j = 0; j < 8; ++j) asm volatile("" : "+v"(kA[r][j]));

        // ---- gather this thread's 8 z elements into registers ----
        float zre[8], zim[8];
        if (s == 0) {
#pragma unroll
            for (int j = 0; j < 8; ++j) {
                float2 zc = z0[colbase + j * 64];
                zre[j] = zc.x; zim[j] = zc.y;
            }
        } else {
            const float2* zsrc = (s & 1) ? zb1 : zb0;
            const unsigned tag = (unsigned)(s & 7);
            unsigned long long v[8];
#pragma unroll
            for (int j = 0; j < 8; ++j)          // 8 sc loads in flight
                v[j] = zload_u64(zsrc + colbase + j * 64);
            unsigned stale = 0u;
#pragma unroll
            for (int j = 0; j < 8; ++j)
                stale |= (((unsigned)v[j] & 7u) != tag) ? (1u << j) : 0u;
            while (stale) {                      // batched re-poll
                __builtin_amdgcn_s_sleep(1);
#pragma unroll
                for (int j = 0; j < 8; ++j)
                    if (stale & (1u << j))
                        v[j] = zload_u64(zsrc + colbase + j * 64);
#pragma unroll
                for (int j = 0; j < 8; ++j)
                    if ((stale & (1u << j)) && ((unsigned)v[j] & 7u) == tag)
                        stale &= ~(1u << j);
            }
#pragma unroll
            for (int j = 0; j < 8; ++j) {
                union { unsigned u; float f; } cx, cy;
                cx.u = (unsigned)v[j];
                cy.u = (unsigned)(v[j] >> 32);
                zre[j] = cx.f; zim[j] = cy.f;
            }
        }

        // ---- dots: 16 rows x 8 cols per thread, K and z in registers ----
        float sr[16], si[16];
#pragma unroll
        for (int r = 0; r < 16; ++r) { sr[r] = 0.f; si[r] = 0.f; }
#pragma unroll
        for (int j = 0; j < 8; ++j) {
#pragma unroll
            for (int r = 0; r < 16; ++r) {
                sr[r] += kA[r][j] * zre[j];
                si[r] += kA[r][j] * zim[j];
            }
        }

        // ---- distribute-and-halve butterfly: 31 shuffles/thread ----
        // acc index i: i<16 -> Re(row i); i>=16 -> Im(row i-16).
        // Round k keeps indices whose bit k matches lane bit k.
        float a32[32];
#pragma unroll
        for (int r = 0; r < 16; ++r) { a32[r] = sr[r]; a32[16 + r] = si[r]; }
        float b16[16];
#pragma unroll
        for (int m = 0; m < 16; ++m) {
            float aa = a32[2 * m], bb = a32[2 * m + 1];
            bool hi = lane & 1;
            float snd = hi ? aa : bb, kp = hi ? bb : aa;
            b16[m] = kp + __shfl_xor(snd, 1, 64);
        }
        float b8[8];
#pragma unroll
        for (int m = 0; m < 8; ++m) {
            float aa = b16[2 * m], bb = b16[2 * m + 1];
            bool hi = lane & 2;
            float snd = hi ? aa : bb, kp = hi ? bb : aa;
            b8[m] = kp + __shfl_xor(snd, 2, 64);
        }
        float b4[4];
#pragma unroll
        for (int m = 0; m < 4; ++m) {
            float aa = b8[2 * m], bb = b8[2 * m + 1];
            bool hi = lane & 4;
            float snd = hi ? aa : bb, kp = hi ? bb : aa;
            b4[m] = kp + __shfl_xor(snd, 4, 64);
        }
        float b2[2];
#pragma unroll
        for (int m = 0; m < 2; ++m) {
            float aa = b4[2 * m], bb = b4[2 * m + 1];
            bool hi = lane & 8;
            float snd = hi ? aa : bb, kp = hi ? bb : aa;
            b2[m] = kp + __shfl_xor(snd, 8, 64);
        }
        {
            float aa = b2[0], bb = b2[1];
            bool hi = lane & 16;
            float snd = hi ? aa : bb, kp = hi ? bb : aa;
            float red = kp + __shfl_xor(snd, 16, 64);
            // lane l holds acc index (l&31), summed over its 32-lane half
            P[s & 1][w][lane] = red;
        }
        __syncthreads();

        // ---- per-row ODE update (wave 0, lanes 0..15) + publish ----
        if (w == 0 && lane < 16) {
            const int par = s & 1;
            float u = 0.f, vv = 0.f;
#pragma unroll
            for (int q = 0; q < 8; ++q) {
                u  += P[par][q][lane]      + P[par][q][32 + lane];
                vv += P[par][q][16 + lane] + P[par][q][48 + lane];
            }
            float A = x * x - y * y;           // Re(z^2)
            float B = 2.0f * x * y;            // Im(z^2)
            float dzr = inv2n * (u  - (u * A + vv * B)) + omega * x;
            float dzi = inv2n * (vv - (u * B - vv * A)) + omega * y;
            float nx = x + dt * dzr;
            float ny = y + dt * dzi;
            float a2 = nx * nx + ny * ny;
            if (a2 >= 0.999f * 0.999f) {
                float sc = 0.999f / sqrtf(a2);
                nx *= sc; ny *= sc;
            }
            x = nx; y = ny;                    // keep exact state in registers
            int gr = bid * 16 + lane;
            if (s == NSTEPS - 1) {
                zfinal[gr] = make_float2(nx, ny);    // plain, untagged
            } else {
                union { float f; unsigned u; } cx, cy;
                cx.f = nx; cy.f = ny;
                cx.u = (cx.u & ~7u) | (unsigned)((s + 1) & 7);  // tag in x LSBs
                unsigned long long pk =
                    (unsigned long long)cx.u |
                    ((unsigned long long)cy.u << 32);
                float2* zo = ((s + 1) & 1) ? zb1 : zb0;
                zstore_u64(zo + gr, pk);             // fire-and-forget
            }
        }
        // no trailing barrier — P is parity-double-buffered and the tag
        // protocol transitively orders (s+2)-writes after (s)-reads
    }
}

// ---- generic fallback: per-step launches ----
__global__ __launch_bounds__(256) void k_step_f32(
    const float* __restrict__ K, const float2* __restrict__ zin,
    float2* __restrict__ zout, const float* __restrict__ omega_p,
    const float* __restrict__ dt_p, int n) {
    const int wave = threadIdx.x >> 6;
    const int lane = threadIdx.x & 63;
    const int row  = blockIdx.x * 4 + wave;
    if (row >= n) return;
    float sr = 0.0f, si = 0.0f;
    for (int c = lane; c < n; c += 64) {
        float k = K[(size_t)row * n + c];
        float2 z = zin[c];
        sr += k * z.x;
        si += k * z.y;
    }
#pragma unroll
    for (int off = 32; off; off >>= 1) {
        sr += __shfl_down(sr, off, 64);
        si += __shfl_down(si, off, 64);
    }
    if (lane == 0) {
        float u = sr, v = si;
        float2 zc = zin[row];
        float x = zc.x, y = zc.y;
        float inv2n = 1.0f / (2.0f * n);
        float A = x * x - y * y, B = 2.0f * x * y;
        float dzr = inv2n * (u - (u * A + v * B)) + (*omega_p) * x;
        float dzi = inv2n * (v - (u * B - v * A)) + (*omega_p) * y;
        float nx = x + (*dt_p) * dzr, ny = y + (*dt_p) * dzi;
        float a2 = nx * nx + ny * ny;
        if (a2 >= 0.999f * 0.999f) { float sc = 0.999f / sqrtf(a2); nx *= sc; ny *= sc; }
        zout[row] = make_float2(nx, ny);
    }
}

extern "C" void kernel_launch(void* const* d_in, const int* in_sizes, int n_in,
                              void* d_out, int out_size, void* d_ws, size_t ws_size,
                              hipStream_t stream) {
    const float2* z0      = (const float2*)d_in[0];
    const float*  K       = (const float*)d_in[1];
    const float*  omega_p = (const float*)d_in[2];
    const float*  dt_p    = (const float*)d_in[3];
    const int n = in_sizes[0] / 2;
    float2* out = (float2*)d_out;

    const size_t need = 2 * (size_t)NN * sizeof(float2);   // two z buffers
    if (n == NN && ws_size >= need) {
        float2* zb0 = (float2*)d_ws;
        float2* zb1 = zb0 + NN;
        hipMemsetAsync(d_ws, 0, need, stream);   // tag 0 != any live tag (1,2)
        k_persist<<<NBLK, TPB, 0, stream>>>(K, z0, zb0, zb1, out,
                                            omega_p, dt_p);
    } else {
        float2* zb0 = (float2*)d_ws;
        float2* zb1 = zb0 + n;
        const float2* cur = z0;
        for (int s = 0; s < NSTEPS; ++s) {
            float2* nxt = (s == NSTEPS - 1) ? out : ((s & 1) ? zb1 : zb0);
            k_step_f32<<<(n + 3) / 4, 256, 0, stream>>>(K, cur, nxt, omega_p, dt_p, n);
            cur = nxt;
        }
    }
}

// Round 4
// 392.622 us; speedup vs baseline: 2.3066x; 1.1661x over previous
//
#include <hip/hip_runtime.h>

#define NN 4096
#define NSTEPS 100
#define TPB 512
#define NBLK 256     // 1 block per CU; 16 rows per block, K pinned in VGPRs

// Coherent (cross-XCD) 8-byte load/store: relaxed agent-scope atomics compile
// to sc-flagged global ops that bypass the non-coherent L1/L2 and hit the
// coherence point directly — no release/acquire cache-maintenance.
__device__ __forceinline__ void zstore_u64(float2* p, unsigned long long u) {
    __hip_atomic_store((unsigned long long*)p, u, __ATOMIC_RELAXED,
                       __HIP_MEMORY_SCOPE_AGENT);
}
__device__ __forceinline__ unsigned long long zload_u64(const float2* p) {
    return __hip_atomic_load((const unsigned long long*)p, __ATOMIC_RELAXED,
                             __HIP_MEMORY_SCOPE_AGENT);
}

// R5 (on top of R4's direct-to-register tagged exchange):
//  1. EARLY-ISSUE next-step polls: the 8 tagged sc loads for step s+1 are
//     issued right after the dot loop consumes z_s — they fly during the
//     butterfly + barrier + ODE (~0.5us), so the first coherent RTT is off
//     the critical path. Loop top only tag-checks and re-polls stragglers.
//     Safety: buffer (s+1)&1 holds tag s-1 or s+1 (distance 2 mod 8) and
//     8B atomic loads can't tear.
//  2. PER-WAVE distributed ODE: wave w owns rows 2w,2w+1. After the barrier
//     each wave does ONE LDS read per lane from padded P[2][8][68] (pad
//     breaks the 8-way q-stride bank conflict), 5 shfl_xor to finish the
//     cross-wave reduce, and lanes 0/32 keep persistent (x,y), compute the
//     ODE and publish. Removes wave0's serial 32-LDS-read + 16-lane tail.
//  LDS reuse safety at step s+2 (same P parity): any block's tag-(s+2)
//  publish transitively requires tag-(s+1) from ALL 256 blocks (its waves'
//  column gates cover all rows), and each of our waves publishes tag s+1
//  only after its own step-s P-read — so no (s+2)-write precedes an
//  (s)-read anywhere.
__global__ __launch_bounds__(TPB, 2) void k_persist(
    const float* __restrict__ K, const float2* __restrict__ z0,
    float2* __restrict__ zb0, float2* __restrict__ zb1,
    float2* __restrict__ zfinal, const float* __restrict__ omega_p,
    const float* __restrict__ dt_p) {
    __shared__ float P[2][8][68];   // 68: +4 pad so q-stride hits new banks

    const int tid  = threadIdx.x;
    const int bid  = blockIdx.x;
    const int w    = tid >> 6, lane = tid & 63;   // w = column-eighth
    const int colbase = w * 512 + lane;           // col_j = colbase + j*64

    const float omega = *omega_p;
    const float dt    = *dt_p;
    const float inv2n = 1.0f / (2.0f * NN);

    // ---- K fragment: 16 rows x 8 strided cols = 128 scalars in VGPRs ----
    float kA[16][8];
#pragma unroll
    for (int r = 0; r < 16; ++r) {
        const float* Kr = K + (size_t)(bid * 16 + r) * NN + colbase;
#pragma unroll
        for (int j = 0; j < 8; ++j) kA[r][j] = Kr[j * 64];
    }

    // ---- persistent ODE state: wave w's lanes 0/32 hold rows 2w, 2w+1 ----
    float x = 0.f, y = 0.f;
    if ((lane & 31) == 0) {
        float2 zc = z0[bid * 16 + 2 * w + (lane >> 5)];
        x = zc.x; y = zc.y;
    }

    unsigned long long v[8];   // in-flight tagged loads for the NEXT step

    for (int s = 0; s < NSTEPS; ++s) {
        // Pin kA in registers: opaque redefinition each iteration so the
        // compiler can neither spill-and-reload nor refold the global loads.
#pragma unroll
        for (int r = 0; r < 16; ++r)
#pragma unroll
            for (int j = 0; j < 8; ++j) asm volatile("" : "+v"(kA[r][j]));

        // ---- gather this thread's 8 z elements into registers ----
        float zre[8], zim[8];
        if (s == 0) {
#pragma unroll
            for (int j = 0; j < 8; ++j) {
                float2 zc = z0[colbase + j * 64];
                zre[j] = zc.x; zim[j] = zc.y;
            }
        } else {
            // v[] was issued at the end of step s-1; finish the poll.
            const float2* zsrc = (s & 1) ? zb1 : zb0;
            const unsigned tag = (unsigned)(s & 7);
            unsigned stale = 0u;
#pragma unroll
            for (int j = 0; j < 8; ++j)
                stale |= (((unsigned)v[j] & 7u) != tag) ? (1u << j) : 0u;
            while (stale) {                      // batched re-poll
                __builtin_amdgcn_s_sleep(1);
#pragma unroll
                for (int j = 0; j < 8; ++j)
                    if (stale & (1u << j))
                        v[j] = zload_u64(zsrc + colbase + j * 64);
#pragma unroll
                for (int j = 0; j < 8; ++j)
                    if ((stale & (1u << j)) && ((unsigned)v[j] & 7u) == tag)
                        stale &= ~(1u << j);
            }
#pragma unroll
            for (int j = 0; j < 8; ++j) {
                union { unsigned u; float f; } cx, cy;
                cx.u = (unsigned)v[j];
                cy.u = (unsigned)(v[j] >> 32);
                zre[j] = cx.f; zim[j] = cy.f;
            }
        }

        // ---- dots: 16 rows x 8 cols per thread, K and z in registers ----
        float sr[16], si[16];
#pragma unroll
        for (int r = 0; r < 16; ++r) { sr[r] = 0.f; si[r] = 0.f; }
#pragma unroll
        for (int j = 0; j < 8; ++j) {
#pragma unroll
            for (int r = 0; r < 16; ++r) {
                sr[r] += kA[r][j] * zre[j];
                si[r] += kA[r][j] * zim[j];
            }
        }

        // ---- EARLY-ISSUE the next step's tagged loads (fly during
        //      butterfly + barrier + ODE; checked at next loop top) ----
        if (s + 1 < NSTEPS) {
            const float2* zn = ((s + 1) & 1) ? zb1 : zb0;
#pragma unroll
            for (int j = 0; j < 8; ++j)
                v[j] = zload_u64(zn + colbase + j * 64);
        }

        // ---- distribute-and-halve butterfly: 31 shuffles/thread ----
        // acc index i: i<16 -> Re(row i); i>=16 -> Im(row i-16).
        float a32[32];
#pragma unroll
        for (int r = 0; r < 16; ++r) { a32[r] = sr[r]; a32[16 + r] = si[r]; }
        float b16[16];
#pragma unroll
        for (int m = 0; m < 16; ++m) {
            float aa = a32[2 * m], bb = a32[2 * m + 1];
            bool hi = lane & 1;
            float snd = hi ? aa : bb, kp = hi ? bb : aa;
            b16[m] = kp + __shfl_xor(snd, 1, 64);
        }
        float b8[8];
#pragma unroll
        for (int m = 0; m < 8; ++m) {
            float aa = b16[2 * m], bb = b16[2 * m + 1];
            bool hi = lane & 2;
            float snd = hi ? aa : bb, kp = hi ? bb : aa;
            b8[m] = kp + __shfl_xor(snd, 2, 64);
        }
        float b4[4];
#pragma unroll
        for (int m = 0; m < 4; ++m) {
            float aa = b8[2 * m], bb = b8[2 * m + 1];
            bool hi = lane & 4;
            float snd = hi ? aa : bb, kp = hi ? bb : aa;
            b4[m] = kp + __shfl_xor(snd, 4, 64);
        }
        float b2[2];
#pragma unroll
        for (int m = 0; m < 2; ++m) {
            float aa = b4[2 * m], bb = b4[2 * m + 1];
            bool hi = lane & 8;
            float snd = hi ? aa : bb, kp = hi ? bb : aa;
            b2[m] = kp + __shfl_xor(snd, 8, 64);
        }
        {
            float aa = b2[0], bb = b2[1];
            bool hi = lane & 16;
            float snd = hi ? aa : bb, kp = hi ? bb : aa;
            float red = kp + __shfl_xor(snd, 16, 64);
            // lane l holds acc index (l&31), summed over its 32-lane half
            P[s & 1][w][lane] = red;
        }
        __syncthreads();

        // ---- per-wave ODE: wave w owns rows 2w, 2w+1 ----
        {
            const int par = s & 1;
            const int r0 = 2 * w, r1 = 2 * w + 1;
            int q    = lane & 7;
            int half = (lane >> 3) & 1;
            int sel  = lane >> 4;                       // 0..3
            int rr   = (sel & 2) ? r1 : r0;
            int idx  = ((sel & 1) << 4) + rr;           // +16 selects Im
            float val = P[par][q][half * 32 + idx];
            val += __shfl_xor(val, 1, 64);              // sum over q
            val += __shfl_xor(val, 2, 64);
            val += __shfl_xor(val, 4, 64);
            val += __shfl_xor(val, 8, 64);              // sum the two halves
            float other = __shfl_xor(val, 16, 64);      // Im to lanes 0/32
            if ((lane & 31) == 0) {                     // lanes 0 and 32
                float u  = val;                         // Re(K z) row
                float vv = other;                       // Im(K z) row
                float A = x * x - y * y;                // Re(z^2)
                float B = 2.0f * x * y;                 // Im(z^2)
                float dzr = inv2n * (u  - (u * A + vv * B)) + omega * x;
                float dzi = inv2n * (vv - (u * B - vv * A)) + omega * y;
                float nx = x + dt * dzr;
                float ny = y + dt * dzi;
                float a2 = nx * nx + ny * ny;
                if (a2 >= 0.999f * 0.999f) {
                    float sc = 0.999f / sqrtf(a2);
                    nx *= sc; ny *= sc;
                }
                x = nx; y = ny;                         // state stays in regs
                int gr = bid * 16 + r0 + (lane >> 5);
                if (s == NSTEPS - 1) {
                    zfinal[gr] = make_float2(nx, ny);   // plain, untagged
                } else {
                    union { float f; unsigned u; } cx, cy;
                    cx.f = nx; cy.f = ny;
                    cx.u = (cx.u & ~7u) | (unsigned)((s + 1) & 7);
                    unsigned long long pk =
                        (unsigned long long)cx.u |
                        ((unsigned long long)cy.u << 32);
                    float2* zo = ((s + 1) & 1) ? zb1 : zb0;
                    zstore_u64(zo + gr, pk);            // fire-and-forget
                }
            }
        }
        // no trailing barrier — P is parity-double-buffered and the tag
        // protocol transitively orders (s+2)-writes after (s)-reads
    }
}

// ---- generic fallback: per-step launches ----
__global__ __launch_bounds__(256) void k_step_f32(
    const float* __restrict__ K, const float2* __restrict__ zin,
    float2* __restrict__ zout, const float* __restrict__ omega_p,
    const float* __restrict__ dt_p, int n) {
    const int wave = threadIdx.x >> 6;
    const int lane = threadIdx.x & 63;
    const int row  = blockIdx.x * 4 + wave;
    if (row >= n) return;
    float sr = 0.0f, si = 0.0f;
    for (int c = lane; c < n; c += 64) {
        float k = K[(size_t)row * n + c];
        float2 z = zin[c];
        sr += k * z.x;
        si += k * z.y;
    }
#pragma unroll
    for (int off = 32; off; off >>= 1) {
        sr += __shfl_down(sr, off, 64);
        si += __shfl_down(si, off, 64);
    }
    if (lane == 0) {
        float u = sr, v = si;
        float2 zc = zin[row];
        float x = zc.x, y = zc.y;
        float inv2n = 1.0f / (2.0f * n);
        float A = x * x - y * y, B = 2.0f * x * y;
        float dzr = inv2n * (u - (u * A + v * B)) + (*omega_p) * x;
        float dzi = inv2n * (v - (u * B - v * A)) + (*omega_p) * y;
        float nx = x + (*dt_p) * dzr, ny = y + (*dt_p) * dzi;
        float a2 = nx * nx + ny * ny;
        if (a2 >= 0.999f * 0.999f) { float sc = 0.999f / sqrtf(a2); nx *= sc; ny *= sc; }
        zout[row] = make_float2(nx, ny);
    }
}

extern "C" void kernel_launch(void* const* d_in, const int* in_sizes, int n_in,
                              void* d_out, int out_size, void* d_ws, size_t ws_size,
                              hipStream_t stream) {
    const float2* z0      = (const float2*)d_in[0];
    const float*  K       = (const float*)d_in[1];
    const float*  omega_p = (const float*)d_in[2];
    const float*  dt_p    = (const float*)d_in[3];
    const int n = in_sizes[0] / 2;
    float2* out = (float2*)d_out;

    const size_t need = 2 * (size_t)NN * sizeof(float2);   // two z buffers
    if (n == NN && ws_size >= need) {
        float2* zb0 = (float2*)d_ws;
        float2* zb1 = zb0 + NN;
        hipMemsetAsync(d_ws, 0, need, stream);   // tag 0 != any live tag (1,2)
        k_persist<<<NBLK, TPB, 0, stream>>>(K, z0, zb0, zb1, out,
                                            omega_p, dt_p);
    } else {
        float2* zb0 = (float2*)d_ws;
        float2* zb1 = zb0 + n;
        const float2* cur = z0;
        for (int s = 0; s < NSTEPS; ++s) {
            float2* nxt = (s == NSTEPS - 1) ? out : ((s & 1) ? zb1 : zb0);
            k_step_f32<<<(n + 3) / 4, 256, 0, stream>>>(K, cur, nxt, omega_p, dt_p, n);
            cur = nxt;
        }
    }
}